// Round 3
// baseline (362.239 us; speedup 1.0000x reference)
//
#include <hip/hip_runtime.h>
#include <hip/hip_bf16.h>

// SelfAttention truncated forward: scores = (Xq Wq + bq)(Xk Wk + bk)^T / 8
// Inputs FP32, output FP32 (verified by R0-R2 absmax signatures).
// Internal Q/K kept in bf16 (MFMA), fp32 accumulate — within 0.13 tolerance.
constexpr int Bn = 4;      // batch
constexpr int S  = 4096;   // sequence
constexpr int E  = 512;    // embed dim
constexpr int DK = 64;     // d_k
constexpr int LDS_STRIDE = DK + 8;   // pad 64->72 bf16: <=2-way bank aliasing (free)

typedef __attribute__((ext_vector_type(8))) short   bf16x8;  // MFMA A/B frag (4 VGPRs)
typedef __attribute__((ext_vector_type(4))) float   f32x4;   // MFMA C/D frag / float4

__device__ __forceinline__ unsigned short f2bf(float f) {
    unsigned x = __builtin_bit_cast(unsigned, f);
    unsigned r = x + 0x7FFFu + ((x >> 16) & 1u);   // RNE
    return (unsigned short)(r >> 16);
}

// load 8 consecutive floats, convert to bf16x8
__device__ __forceinline__ bf16x8 load8_f2bf(const float* __restrict__ p) {
    f32x4 a = *(const f32x4*)p;
    f32x4 b = *(const f32x4*)(p + 4);
    bf16x8 o;
    o[0] = (short)f2bf(a[0]); o[1] = (short)f2bf(a[1]);
    o[2] = (short)f2bf(a[2]); o[3] = (short)f2bf(a[3]);
    o[4] = (short)f2bf(b[0]); o[5] = (short)f2bf(b[1]);
    o[6] = (short)f2bf(b[2]); o[7] = (short)f2bf(b[3]);
    return o;
}

// ---------------------------------------------------------------------------
// Kernel 0: transpose+convert W[512][64] (fp32) -> Wt[64][512] (bf16), Wq & Wk.
// ---------------------------------------------------------------------------
__global__ __launch_bounds__(256) void wt_kernel(const float* __restrict__ Wq,
                                                 const float* __restrict__ Wk,
                                                 unsigned short* __restrict__ Wt) {
    int idx = blockIdx.x * 256 + threadIdx.x;      // 0..32767
    const float* W = blockIdx.y ? Wk : Wq;
    int n = idx >> 9;        // output row (0..63)
    int k = idx & 511;       // output col (0..511)
    Wt[blockIdx.y * (DK * E) + idx] = f2bf(W[k * DK + n]);
}

// ---------------------------------------------------------------------------
// Kernel 1: projection  P[16384][64] = X[16384][512] @ W[512][64] + b
// X fp32 -> bf16 during LDS staging; bf16 MFMA; P stored bf16 (workspace).
// blockIdx.y: 0 -> (query, Wq, bq, Qout), 1 -> (key, Wk, bk, Kout)
// ---------------------------------------------------------------------------
__global__ __launch_bounds__(256) void proj_kernel(const float* __restrict__ Xq,
                                                   const float* __restrict__ Xk,
                                                   const unsigned short* __restrict__ Wt,
                                                   const float* __restrict__ bq,
                                                   const float* __restrict__ bk,
                                                   unsigned short* __restrict__ Qp,
                                                   unsigned short* __restrict__ Kp) {
    const float*          X    = blockIdx.y ? Xk : Xq;
    const unsigned short* Wtm  = Wt + (size_t)blockIdx.y * DK * E;
    const float*          bias = blockIdx.y ? bk : bq;
    unsigned short*       P    = blockIdx.y ? Kp : Qp;

    __shared__ unsigned short xs[128][LDS_STRIDE];

    const int tid  = threadIdx.x;
    const int wave = tid >> 6;
    const int lane = tid & 63;
    const int quad = lane >> 4;
    const int l16  = lane & 15;
    const long row0 = (long)blockIdx.x * 128;

    f32x4 acc[2][4];
#pragma unroll
    for (int rt = 0; rt < 2; ++rt)
#pragma unroll
        for (int ct = 0; ct < 4; ++ct) acc[rt][ct] = (f32x4){0.f, 0.f, 0.f, 0.f};

    for (int k0 = 0; k0 < E; k0 += 64) {
        __syncthreads();   // protect xs reuse across iterations
        // stage X[row0:+128][k0:+64] (fp32) -> xs (bf16), 1024 chunks of 8
#pragma unroll
        for (int c = tid; c < 1024; c += 256) {
            int r  = c >> 3;
            int kc = (c & 7) * 8;
            *(bf16x8*)&xs[r][kc] = load8_f2bf(&X[(row0 + r) * E + k0 + kc]);
        }
        __syncthreads();

        // B fragments straight from global Wt (64 KiB bf16, L1/L2 resident)
        bf16x8 bfrag[2][4];
#pragma unroll
        for (int kc = 0; kc < 2; ++kc)
#pragma unroll
            for (int ct = 0; ct < 4; ++ct)
                bfrag[kc][ct] = *(const bf16x8*)&Wtm[(size_t)(ct * 16 + l16) * E + k0 + kc * 32 + quad * 8];

#pragma unroll
        for (int rt = 0; rt < 2; ++rt) {
#pragma unroll
            for (int kc = 0; kc < 2; ++kc) {
                bf16x8 afrag = *(const bf16x8*)&xs[wave * 32 + rt * 16 + l16][kc * 32 + quad * 8];
#pragma unroll
                for (int ct = 0; ct < 4; ++ct)
                    acc[rt][ct] = __builtin_amdgcn_mfma_f32_16x16x32_bf16(afrag, bfrag[kc][ct], acc[rt][ct], 0, 0, 0);
            }
        }
    }

    // epilogue: + bias (fp32), convert, store (C/D layout: col=lane&15, row=quad*4+r)
#pragma unroll
    for (int ct = 0; ct < 4; ++ct) {
        float bv = bias[ct * 16 + l16];
#pragma unroll
        for (int rt = 0; rt < 2; ++rt) {
#pragma unroll
            for (int r = 0; r < 4; ++r) {
                long row = row0 + wave * 32 + rt * 16 + quad * 4 + r;
                P[row * DK + ct * 16 + l16] = f2bf(acc[rt][ct][r] + bv);
            }
        }
    }
}

// ---------------------------------------------------------------------------
// Kernel 2: scores[b][q][k] = Q[b][q][:] . K[b][k][:] * 0.125   (FP32 out)
// 128x128 output tile per block; whole K-dim (64) staged once in LDS.
// ---------------------------------------------------------------------------
__global__ __launch_bounds__(256) void score_kernel(const unsigned short* __restrict__ Q,
                                                    const unsigned short* __restrict__ K,
                                                    float* __restrict__ out) {
    __shared__ unsigned short qs[128][LDS_STRIDE];
    __shared__ unsigned short ks[128][LDS_STRIDE];

    const int tid  = threadIdx.x;
    const int wave = tid >> 6;
    const int lane = tid & 63;
    const int quad = lane >> 4;
    const int l16  = lane & 15;

    const int  b     = blockIdx.z;
    const long qrow0 = (long)blockIdx.y * 128;
    const long krow0 = (long)blockIdx.x * 128;
    const unsigned short* Qb = Q + (size_t)b * S * DK;
    const unsigned short* Kb = K + (size_t)b * S * DK;

#pragma unroll
    for (int c = tid; c < 1024; c += 256) {
        int r  = c >> 3;
        int kc = (c & 7) * 8;
        *(bf16x8*)&qs[r][kc] = *(const bf16x8*)&Qb[(qrow0 + r) * DK + kc];
        *(bf16x8*)&ks[r][kc] = *(const bf16x8*)&Kb[(krow0 + r) * DK + kc];
    }
    __syncthreads();

    const int wr = (wave >> 1) * 64;   // wave's row offset within the 128-tile
    const int wc = (wave & 1) * 64;    // wave's col offset

    bf16x8 afrag[4][2], bfrag[4][2];
#pragma unroll
    for (int rt = 0; rt < 4; ++rt)
#pragma unroll
        for (int kc = 0; kc < 2; ++kc)
            afrag[rt][kc] = *(const bf16x8*)&qs[wr + rt * 16 + l16][kc * 32 + quad * 8];
#pragma unroll
    for (int ct = 0; ct < 4; ++ct)
#pragma unroll
        for (int kc = 0; kc < 2; ++kc)
            bfrag[ct][kc] = *(const bf16x8*)&ks[wc + ct * 16 + l16][kc * 32 + quad * 8];

    f32x4 acc[4][4];
#pragma unroll
    for (int rt = 0; rt < 4; ++rt)
#pragma unroll
        for (int ct = 0; ct < 4; ++ct) acc[rt][ct] = (f32x4){0.f, 0.f, 0.f, 0.f};

#pragma unroll
    for (int rt = 0; rt < 4; ++rt)
#pragma unroll
        for (int ct = 0; ct < 4; ++ct)
#pragma unroll
            for (int kc = 0; kc < 2; ++kc)
                acc[rt][ct] = __builtin_amdgcn_mfma_f32_16x16x32_bf16(afrag[rt][kc], bfrag[ct][kc], acc[rt][ct], 0, 0, 0);

    float* ob = out + (size_t)b * S * S;
#pragma unroll
    for (int rt = 0; rt < 4; ++rt) {
#pragma unroll
        for (int ct = 0; ct < 4; ++ct) {
#pragma unroll
            for (int r = 0; r < 4; ++r) {
                long row = qrow0 + wr + rt * 16 + quad * 4 + r;
                long col = krow0 + wc + ct * 16 + l16;
                ob[row * S + col] = acc[rt][ct][r] * 0.125f;
            }
        }
    }
}

// ---------------------------------------------------------------------------
extern "C" void kernel_launch(void* const* d_in, const int* in_sizes, int n_in,
                              void* d_out, int out_size, void* d_ws, size_t ws_size,
                              hipStream_t stream) {
    (void)in_sizes; (void)n_in; (void)out_size; (void)ws_size;

    const float* query = (const float*)d_in[0];
    const float* key   = (const float*)d_in[1];
    const float* Wq    = (const float*)d_in[3];
    const float* bq    = (const float*)d_in[4];
    const float* Wk    = (const float*)d_in[5];
    const float* bk    = (const float*)d_in[6];
    // value_in / Wv / bv (d_in[2], d_in[7], d_in[8]) are dead code in the reference.

    unsigned short* ws = (unsigned short*)d_ws;
    unsigned short* Wt = ws;                       // [2][64][512] bf16   (128 KiB)
    unsigned short* Qp = ws + 2 * DK * E;          // [4][4096][64] bf16  (2 MiB)
    unsigned short* Kp = Qp + (size_t)Bn * S * DK; // [4][4096][64] bf16  (2 MiB)

    float* scores = (float*)d_out;

    wt_kernel<<<dim3(128, 2), 256, 0, stream>>>(Wq, Wk, Wt);
    proj_kernel<<<dim3(Bn * S / 128, 2), 256, 0, stream>>>(query, key, Wt, bq, bk, Qp, Kp);
    score_kernel<<<dim3(S / 128, S / 128, Bn), 256, 0, stream>>>(Qp, Kp, scores);
}